// Round 5
// baseline (253.065 us; speedup 1.0000x reference)
//
#include <hip/hip_runtime.h>

// LSTM: B=32768, T=28, D=28, H=8, gates=32, classes=10.
// 32 lanes per batch element; lane g owns gate COLUMN g of W (36 fp32 = 36
// VGPRs -- small enough that the RA keeps it resident without any fight;
// rounds 2-4 showed the AMDGPU RA remats/spills anything pushing past its
// ~4-wave/EU register target, so we fit UNDER that target instead).
// Columns: 0-7 = i, 8-15 = j, 16-23 = f, 24-31 = o (BasicLSTMCell order).
// After the 36-FMA dot, 3 shfl_xor gather (i,j,f,o) onto lanes 0-7; all
// lanes run the activation (garbage on 8-31, never read); h round-trips
// through an 8-float LDS slot (wave-synchronous, broadcast reads).
// 4096 blocks x 256 threads = 16384 waves = 16 work-waves/SIMD.

#define TSTEPS 28
#define DIN    28
#define NH     8
#define NG     32
#define NC     10
#define NROWS  36   // DIN + NH

__device__ __forceinline__ float fast_exp2(float x) {
    return __builtin_amdgcn_exp2f(x);
}
__device__ __forceinline__ float fast_rcp(float x) {
    return __builtin_amdgcn_rcpf(x);
}
__device__ __forceinline__ float fast_sigmoid(float z) {
    return fast_rcp(1.0f + fast_exp2(-1.4426950408889634f * z));
}
__device__ __forceinline__ float fast_tanh(float z) {
    return 1.0f - 2.0f * fast_rcp(1.0f + fast_exp2(2.8853900817779268f * z));
}

__global__ __launch_bounds__(256, 4) void lstm_kernel(
    const float* __restrict__ x,      // [B, T, D]
    const float* __restrict__ W,      // [36, 32]  col order i,j,f,o
    const float* __restrict__ bias,   // [32]
    const float* __restrict__ Wout,   // [8, 10]
    const float* __restrict__ bout,   // [10]
    float* __restrict__ out)          // [B, 10]
{
    const int tid  = blockIdx.x * 256 + threadIdx.x;
    const int e    = tid >> 5;             // batch element
    const int g    = tid & 31;             // gate column owned by this lane
    const int widx = threadIdx.x >> 5;     // element slot within block (0..7)

    // 8 h-values per element slot; float4-aligned, broadcast reads.
    __shared__ __align__(16) float hsm[8][NH];

    const float* xb = x + (size_t)e * (TSTEPS * DIN);

    // Lane's W column: 36 values, coalesced loads, stays in VGPRs.
    float Wc[NROWS];
#pragma unroll
    for (int k = 0; k < NROWS; ++k)
        Wc[k] = W[k * NG + g];
    const float bg = bias[g];

    float c = 0.0f;
    float hall[NH];
#pragma unroll
    for (int j = 0; j < NH; ++j) hall[j] = 0.0f;

    // x double buffer: row = 112 B = 7 aligned float4
    float4 xq[2][7];
    {
        const float4* xv = (const float4*)xb;
#pragma unroll
        for (int i = 0; i < 7; ++i) xq[0][i] = xv[i];
    }

    auto do_step = [&](float4 (&cur)[7], float4 (&nxt)[7], int tnext) {
        if (tnext < TSTEPS) {
            const float4* xv = (const float4*)(xb + tnext * DIN);
#pragma unroll
            for (int i = 0; i < 7; ++i) nxt[i] = xv[i];
        }

        // gate_g = b_g + x . Wc[0:28] + h . Wc[28:36]   (36 FMA)
        float acc = bg;
#pragma unroll
        for (int i = 0; i < 7; ++i) {
            acc = fmaf(cur[i].x, Wc[4*i+0], acc);
            acc = fmaf(cur[i].y, Wc[4*i+1], acc);
            acc = fmaf(cur[i].z, Wc[4*i+2], acc);
            acc = fmaf(cur[i].w, Wc[4*i+3], acc);
        }
#pragma unroll
        for (int k = 0; k < NH; ++k)
            acc = fmaf(hall[k], Wc[DIN + k], acc);

        // Gather (i,j,f,o) of unit u onto lane u (u = g&7):
        // lanes u,u+8,u+16,u+24 hold i,j,f,o.
        float v1 = __shfl_xor(acc, 8);    // lane u: j_u
        float v2 = __shfl_xor(acc, 16);   // lane u: f_u
        float v3 = __shfl_xor(v1, 16);    // lane u: o_u

        // All lanes compute; only lanes 0-7 (per 32-group) hold real values.
        float ig = fast_sigmoid(acc);
        float jg = fast_tanh(v1);
        float fg = fast_sigmoid(v2 + 1.0f);
        float og = fast_sigmoid(v3);
        c = c * fg + ig * jg;
        float hu = fast_tanh(c) * og;

        // h exchange through LDS (wave-synchronous: writer and readers are
        // the same wave; wave_barrier pins compile-time ordering).
        if (g < NH) hsm[widx][g] = hu;
        __builtin_amdgcn_wave_barrier();
        float4 h01 = *(const float4*)&hsm[widx][0];
        float4 h23 = *(const float4*)&hsm[widx][4];
        __builtin_amdgcn_wave_barrier();
        hall[0] = h01.x; hall[1] = h01.y; hall[2] = h01.z; hall[3] = h01.w;
        hall[4] = h23.x; hall[5] = h23.y; hall[6] = h23.z; hall[7] = h23.w;
    };

#pragma unroll 1
    for (int tt = 0; tt < TSTEPS; tt += 2) {
        do_step(xq[0], xq[1], tt + 1);
        do_step(xq[1], xq[0], tt + 2);
    }

    // logits = h @ Wout + bout; lanes 0-9 of each 32-group write one column
    if (g < NC) {
        float acc = bout[g];
#pragma unroll
        for (int k = 0; k < NH; ++k)
            acc = fmaf(hall[k], Wout[k * NC + g], acc);
        out[(size_t)e * NC + g] = acc;
    }
}

extern "C" void kernel_launch(void* const* d_in, const int* in_sizes, int n_in,
                              void* d_out, int out_size, void* d_ws, size_t ws_size,
                              hipStream_t stream) {
    const float* x    = (const float*)d_in[0];
    const float* W    = (const float*)d_in[1];
    const float* b    = (const float*)d_in[2];
    const float* Wout = (const float*)d_in[3];
    const float* bout = (const float*)d_in[4];
    float* out = (float*)d_out;

    const int B = in_sizes[0] / (TSTEPS * DIN);  // 32768
    const int threads = B * NG;                  // 1048576
    const int block = 256;
    const int grid = threads / block;            // 4096
    lstm_kernel<<<grid, block, 0, stream>>>(x, W, b, Wout, bout, out);
}